// Round 5
// baseline (79.114 us; speedup 1.0000x reference)
//
#include <hip/hip_runtime.h>
#include <hip/hip_cooperative_groups.h>
#include <hip/hip_bf16.h>
#include <math.h>

#define SRATE 48000.0
#define SEGSZ 960
#define NHARM 8
#define LFRM 250
#define LWAVE (LFRM * SEGSZ)   // 240000
#define CCH 256

namespace cg = cooperative_groups;

// ---------------------------------------------------------------------------
// Phase 1 body: 1x1 convs for one (n, 64-frame strip).
// block = 256 = 4 waves; wave wv reduces channels [wv*64, wv*64+64),
// lane = frame-in-strip. Loads batched 16-deep to cut latency round trips.
// Weights read with wave-uniform addresses -> scalar loads.
// ---------------------------------------------------------------------------
__device__ __forceinline__ void conv_body(
        int n, int strip,
        const float* __restrict__ x,
        const float* __restrict__ w_mag, const float* __restrict__ b_mag,
        const float* __restrict__ w_oct, const float* __restrict__ b_oct,
        float* __restrict__ f0, float* __restrict__ magbar,
        float* smem) {
    float (*sred)[4][64] = (float (*)[4][64])smem;   // [9][4][64]
    int tid  = threadIdx.x;
    int lane = tid & 63;
    int wv   = tid >> 6;

    int i = strip * 64 + lane;
    bool act = (i < LFRM);
    int ii = act ? i : (LFRM - 1);
    const float* xp = x + (size_t)n * CCH * LFRM + ii;

    float oct = 0.f;
    float mh[NHARM];
#pragma unroll
    for (int h = 0; h < NHARM; ++h) mh[h] = 0.f;

    int c0 = wv * 64;
#pragma unroll
    for (int o = 0; o < 4; ++o) {
        float xv[16];
#pragma unroll
        for (int u = 0; u < 16; ++u)
            xv[u] = xp[(size_t)(c0 + o * 16 + u) * LFRM];
#pragma unroll
        for (int u = 0; u < 16; ++u) {
            int c = c0 + o * 16 + u;                 // wave-uniform
            oct = fmaf(w_oct[c], xv[u], oct);
#pragma unroll
            for (int h = 0; h < NHARM; ++h)
                mh[h] = fmaf(w_mag[h * CCH + c], xv[u], mh[h]);
        }
    }
    sred[0][wv][lane] = oct;
#pragma unroll
    for (int h = 0; h < NHARM; ++h) sred[1 + h][wv][lane] = mh[h];
    __syncthreads();

    if (tid < 64 && act) {
        float o = sred[0][0][lane] + sred[0][1][lane]
                + sred[0][2][lane] + sred[0][3][lane] + b_oct[0];
        float f0v = 220.0f * exp2f(o);
        float ms = 0.f;
#pragma unroll
        for (int h = 0; h < NHARM; ++h) {
            float mv = sred[1 + h][0][lane] + sred[1 + h][1][lane]
                     + sred[1 + h][2][lane] + sred[1 + h][3][lane];
            ms += expf(fminf(mv + b_mag[h], 6.0f));
        }
        f0[n * LFRM + i]     = f0v;
        magbar[n * LFRM + i] = ms * (1.0f / NHARM);
    }
}

// ---------------------------------------------------------------------------
// Phase 2 body: scan + synthesis for (n, region-group g), g in [0,16).
// Stage f0/magbar to LDS; wave 0 does the f64 prefix and emits PER-REGION
// f32 phase fractions sfr[k] = frac(phi + P[k]) (sfr[250] = frac(phi) for the
// head), so the synthesis loop is pure f32. 240 active threads, 4 samples
// each, regions k = g*16 .. g*16+15 (k==249 -> head+tail; k>249 skipped).
// ---------------------------------------------------------------------------
__device__ __forceinline__ void wave_body(
        int n, int g,
        const float* __restrict__ f0, const float* __restrict__ magbar,
        const float* __restrict__ phi, float* __restrict__ out,
        float* smem) {
    float* sf0 = smem;          // 250
    float* smb = smem + 256;    // 250
    float* sfr = smem + 512;    // 251

    int tid = threadIdx.x;
    if (tid < LFRM) {
        sf0[tid] = f0[n * LFRM + tid];
        smb[tid] = magbar[n * LFRM + tid];
    }
    __syncthreads();

    if (tid < 64) {                          // wave-0 f64 scan -> f32 fracs
        int lane = tid;
        double ph = (double)phi[n];
        double S[4];
        double local = 0.0;
#pragma unroll
        for (int m = 0; m < 4; ++m) {
            int k = 4 * lane + m;
            double s = 0.0;
            if (k < LFRM - 1)
                s = 480.0 * ((double)sf0[k] + (double)sf0[k + 1]) * (1.0 / SRATE);
            S[m] = s;
            local += s;
        }
        double incl = local;
        for (int off = 1; off < 64; off <<= 1) {
            double up = __shfl_up(incl, off, 64);
            if (lane >= off) incl += up;
        }
        double run = (incl - local) + 480.0 * (double)sf0[0] * (1.0 / SRATE) + ph;
#pragma unroll
        for (int m = 0; m < 4; ++m) {
            int k = 4 * lane + m;
            if (k < LFRM) sfr[k] = (float)(run - floor(run));
            run += S[m];
        }
        if (lane == 0) sfr[LFRM] = (float)(ph - floor(ph));
    }
    __syncthreads();

    if (tid >= 240) return;
    int j0 = tid * 4;

#pragma unroll
    for (int r = 0; r < 16; ++r) {
        int k = g * 16 + r;
        if (k >= LFRM) break;
        float rr[4];
        size_t l0;
        if (k < LFRM - 1) {                  // full region k
            float fk = sf0[k];
            float df = sf0[k + 1] - fk;
            float m0 = smb[k];
            float dm = smb[k + 1] - m0;
            float bf = sfr[k];
            float c1 = fk * (float)(1.0 / SRATE);
            float c2 = df * (float)(1.0 / (2.0 * SEGSZ * SRATE));
            l0 = (size_t)(SEGSZ / 2) + (size_t)k * SEGSZ + j0;
#pragma unroll
            for (int q = 0; q < 4; ++q) {
                float mf = (float)(j0 + q + 1);
                float t  = fmaf(mf, c1, fmaf(mf * mf, c2, bf));
                float fr = t - floorf(t);
                float s  = __builtin_amdgcn_sinf(fr);     // sin(2*pi*fr)
                float w  = ((float)(j0 + q) + 0.5f) * (1.0f / SEGSZ);
                rr[q] = s * fmaf(w, dm, m0);
            }
        } else {                             // k == 249: head + tail
            bool tail = (tid >= 120);
            float fk = tail ? sf0[LFRM - 1] : sf0[0];
            float mg = tail ? smb[LFRM - 1] : smb[0];
            float bf = tail ? sfr[LFRM - 1] : sfr[LFRM];
            float c1 = fk * (float)(1.0 / SRATE);
            int jl = (tail ? (tid - 120) : tid) * 4;
            l0 = (tail ? (size_t)(LWAVE - SEGSZ / 2) : 0) + jl;
#pragma unroll
            for (int q = 0; q < 4; ++q) {
                float mf = (float)(jl + q + 1);
                float t  = fmaf(mf, c1, bf);
                float fr = t - floorf(t);
                rr[q] = __builtin_amdgcn_sinf(fr) * mg;
            }
        }
        *reinterpret_cast<float4*>(out + (size_t)n * LWAVE + l0) =
            make_float4(rr[0], rr[1], rr[2], rr[3]);
    }
}

// ---------------------------------------------------------------------------
// Cooperative fused kernel. grid = 16*N blocks of 256.
// Blocks [0, 4N): conv for (n = bid>>2, strip = bid&3). grid.sync().
// All blocks: synthesis for (n = bid>>4, g = bid&15).
// __launch_bounds__(256,2) caps VGPR <= 128 -> >=4 blocks/CU residency,
// 2x margin for the cooperative co-residency requirement (512 blocks).
// ---------------------------------------------------------------------------
__global__ __launch_bounds__(256, 2) void k_all(
        const float* __restrict__ x, const float* __restrict__ phi,
        const float* __restrict__ w_mag, const float* __restrict__ b_mag,
        const float* __restrict__ w_oct, const float* __restrict__ b_oct,
        float* __restrict__ f0, float* __restrict__ magbar,
        float* __restrict__ out, int N) {
    __shared__ float smem[2304];
    int bid = blockIdx.x;
    if (bid < 4 * N)
        conv_body(bid >> 2, bid & 3, x, w_mag, b_mag, w_oct, b_oct, f0, magbar, smem);
    cg::this_grid().sync();
    wave_body(bid >> 4, bid & 15, f0, magbar, phi, out, smem);
}

// --------------------- non-cooperative fallback path -----------------------
__global__ __launch_bounds__(256) void k_frames_fb(
        const float* __restrict__ x,
        const float* __restrict__ w_mag, const float* __restrict__ b_mag,
        const float* __restrict__ w_oct, const float* __restrict__ b_oct,
        float* __restrict__ f0, float* __restrict__ magbar) {
    __shared__ float smem[2304];
    conv_body(blockIdx.x >> 2, blockIdx.x & 3, x, w_mag, b_mag, w_oct, b_oct,
              f0, magbar, smem);
}

__global__ __launch_bounds__(256) void k_wave_fb(
        const float* __restrict__ f0, const float* __restrict__ magbar,
        const float* __restrict__ phi, float* __restrict__ out) {
    __shared__ float smem[768];
    wave_body(blockIdx.x >> 4, blockIdx.x & 15, f0, magbar, phi, out, smem);
}

// ---------------------------------------------------------------------------
extern "C" void kernel_launch(void* const* d_in, const int* in_sizes, int n_in,
                              void* d_out, int out_size, void* d_ws, size_t ws_size,
                              hipStream_t stream) {
    const float* x     = (const float*)d_in[0];
    const float* phi   = (const float*)d_in[1];
    const float* w_mag = (const float*)d_in[2];
    const float* b_mag = (const float*)d_in[3];
    const float* w_oct = (const float*)d_in[4];
    const float* b_oct = (const float*)d_in[5];
    float* out = (float*)d_out;

    int N = in_sizes[1];          // phi has N elements (N,1,1)

    char* ws = (char*)d_ws;
    float* f0     = (float*)ws;                    // N*250*4
    float* magbar = (float*)(ws + 64 * 1024);      // N*250*4

    void* args[] = { (void*)&x, (void*)&phi, (void*)&w_mag, (void*)&b_mag,
                     (void*)&w_oct, (void*)&b_oct, (void*)&f0, (void*)&magbar,
                     (void*)&out, (void*)&N };
    hipError_t e = hipLaunchCooperativeKernel((const void*)k_all,
                                              dim3(16 * N), dim3(256),
                                              args, 0, stream);
    if (e != hipSuccess) {
        k_frames_fb<<<dim3(4 * N), 256, 0, stream>>>(x, w_mag, b_mag, w_oct,
                                                     b_oct, f0, magbar);
        k_wave_fb<<<dim3(16 * N), 256, 0, stream>>>(f0, magbar, phi, out);
    }
}

// Round 6
// 24.119 us; speedup vs baseline: 3.2801x; 3.2801x over previous
//
#include <hip/hip_runtime.h>
#include <hip/hip_bf16.h>
#include <math.h>

#define SRATE 48000.0
#define SEGSZ 960
#define NHARM 8
#define LFRM 250
#define LWAVE (LFRM * SEGSZ)   // 240000
#define CCH 256
#define RPB 5                  // regions per k_wave block (50*5 = 250)

// ---------------------------------------------------------------------------
// Kernel 1: per-frame 1x1 convs -> f0[n][i], magbar[n][i] (= mean_h mag_h)
// grid = 4N blocks, 256 threads = 4 waves; wave wv reduces channels
// [wv*64, wv*64+64), lane = frame-in-strip. Loads batched 16-deep for MLP;
// weights read with wave-uniform addresses -> scalar loads.
// ---------------------------------------------------------------------------
__global__ __launch_bounds__(256) void k_frames(
        const float* __restrict__ x,
        const float* __restrict__ w_mag, const float* __restrict__ b_mag,
        const float* __restrict__ w_oct, const float* __restrict__ b_oct,
        float* __restrict__ f0, float* __restrict__ magbar) {
    __shared__ float sred[NHARM + 1][4][64];
    int tid  = threadIdx.x;
    int lane = tid & 63;
    int wv   = tid >> 6;
    int n     = blockIdx.x >> 2;
    int strip = blockIdx.x & 3;

    int i = strip * 64 + lane;
    bool act = (i < LFRM);
    int ii = act ? i : (LFRM - 1);
    const float* xp = x + (size_t)n * CCH * LFRM + ii;

    float oct = 0.f;
    float mh[NHARM];
#pragma unroll
    for (int h = 0; h < NHARM; ++h) mh[h] = 0.f;

    int c0 = wv * 64;
#pragma unroll
    for (int o = 0; o < 4; ++o) {
        float xv[16];
#pragma unroll
        for (int u = 0; u < 16; ++u)
            xv[u] = xp[(size_t)(c0 + o * 16 + u) * LFRM];
#pragma unroll
        for (int u = 0; u < 16; ++u) {
            int c = c0 + o * 16 + u;                 // wave-uniform
            oct = fmaf(w_oct[c], xv[u], oct);
#pragma unroll
            for (int h = 0; h < NHARM; ++h)
                mh[h] = fmaf(w_mag[h * CCH + c], xv[u], mh[h]);
        }
    }
    sred[0][wv][lane] = oct;
#pragma unroll
    for (int h = 0; h < NHARM; ++h) sred[1 + h][wv][lane] = mh[h];
    __syncthreads();

    if (tid < 64 && act) {
        float o = sred[0][0][lane] + sred[0][1][lane]
                + sred[0][2][lane] + sred[0][3][lane] + b_oct[0];
        float f0v = 220.0f * exp2f(o);
        float ms = 0.f;
#pragma unroll
        for (int h = 0; h < NHARM; ++h) {
            float mv = sred[1 + h][0][lane] + sred[1 + h][1][lane]
                     + sred[1 + h][2][lane] + sred[1 + h][3][lane];
            ms += expf(fminf(mv + b_mag[h], 6.0f));
        }
        f0[n * LFRM + i]     = f0v;
        magbar[n * LFRM + i] = ms * (1.0f / NHARM);
    }
}

// ---------------------------------------------------------------------------
// Kernel 2: scan + synthesis. grid = (50, N), block = 256.
// Wave 0: loads the f0 row (5 vals/lane, lane owns k=4l..4l+3), f64 prefix
// scan via shfl, writes f32 phase fractions sfr[k] = frac(phi + P[k]) to LDS
// (sfr[250] = frac(phi) for the head). One __syncthreads. Then 240 threads
// synthesize regions k = g*5..g*5+4 (k==249 -> head+tail), 4 samples each,
// float4 stores. f0[k]/magbar[k] read as wave-uniform scalar loads (L2-hot).
// Per-sample math pure f32 (rel phase <= ~14 rev -> ~1e-6 rev error).
// ---------------------------------------------------------------------------
__global__ __launch_bounds__(256) void k_wave(
        const float* __restrict__ f0, const float* __restrict__ magbar,
        const float* __restrict__ phi, float* __restrict__ out) {
    __shared__ float sfr[LFRM + 1];

    int tid = threadIdx.x;
    int n = blockIdx.y;
    int g = blockIdx.x;
    const float* f  = f0 + n * LFRM;
    const float* mb = magbar + n * LFRM;

    if (tid < 64) {
        int lane = tid;
        double ph = (double)phi[n];
        float fv[5];
#pragma unroll
        for (int m = 0; m < 5; ++m) {
            int k = 4 * lane + m;
            fv[m] = (k < LFRM) ? f[k] : 0.f;
        }
        double S[4];
        double local = 0.0;
#pragma unroll
        for (int m = 0; m < 4; ++m) {
            int k = 4 * lane + m;
            double s = 0.0;
            if (k < LFRM - 1)
                s = 480.0 * ((double)fv[m] + (double)fv[m + 1]) * (1.0 / SRATE);
            S[m] = s;
            local += s;
        }
        double incl = local;
        for (int off = 1; off < 64; off <<= 1) {
            double up = __shfl_up(incl, off, 64);
            if (lane >= off) incl += up;
        }
        float f00 = __shfl(fv[0], 0);
        double run = (incl - local) + 480.0 * (double)f00 * (1.0 / SRATE) + ph;
#pragma unroll
        for (int m = 0; m < 4; ++m) {
            int k = 4 * lane + m;
            if (k < LFRM) sfr[k] = (float)(run - floor(run));
            run += S[m];
        }
        if (lane == 0) sfr[LFRM] = (float)(ph - floor(ph));
    }
    __syncthreads();

    if (tid >= 240) return;
    int j0 = tid * 4;

#pragma unroll
    for (int r = 0; r < RPB; ++r) {
        int k = g * RPB + r;
        float rr[4];
        size_t l0;
        if (k < LFRM - 1) {                  // full region k
            float fk = f[k];                 // uniform -> s_load
            float df = f[k + 1] - fk;
            float m0 = mb[k];
            float dm = mb[k + 1] - m0;
            float bf = sfr[k];
            float c1 = fk * (float)(1.0 / SRATE);
            float c2 = df * (float)(1.0 / (2.0 * SEGSZ * SRATE));
            l0 = (size_t)(SEGSZ / 2) + (size_t)k * SEGSZ + j0;
#pragma unroll
            for (int q = 0; q < 4; ++q) {
                float mf = (float)(j0 + q + 1);
                float t  = fmaf(mf, c1, fmaf(mf * mf, c2, bf));
                float fr = t - floorf(t);
                float s  = __builtin_amdgcn_sinf(fr);     // sin(2*pi*fr)
                float w  = ((float)(j0 + q) + 0.5f) * (1.0f / SEGSZ);
                rr[q] = s * fmaf(w, dm, m0);
            }
        } else {                             // k == 249: head + tail
            bool tail = (tid >= 120);
            float fk = tail ? f[LFRM - 1] : f[0];
            float mg = tail ? mb[LFRM - 1] : mb[0];
            float bf = tail ? sfr[LFRM - 1] : sfr[LFRM];
            float c1 = fk * (float)(1.0 / SRATE);
            int jl = (tail ? (tid - 120) : tid) * 4;
            l0 = (tail ? (size_t)(LWAVE - SEGSZ / 2) : 0) + jl;
#pragma unroll
            for (int q = 0; q < 4; ++q) {
                float mf = (float)(jl + q + 1);
                float t  = fmaf(mf, c1, bf);
                float fr = t - floorf(t);
                rr[q] = __builtin_amdgcn_sinf(fr) * mg;
            }
        }
        *reinterpret_cast<float4*>(out + (size_t)n * LWAVE + l0) =
            make_float4(rr[0], rr[1], rr[2], rr[3]);
    }
}

// ---------------------------------------------------------------------------
extern "C" void kernel_launch(void* const* d_in, const int* in_sizes, int n_in,
                              void* d_out, int out_size, void* d_ws, size_t ws_size,
                              hipStream_t stream) {
    const float* x     = (const float*)d_in[0];
    const float* phi   = (const float*)d_in[1];
    const float* w_mag = (const float*)d_in[2];
    const float* b_mag = (const float*)d_in[3];
    const float* w_oct = (const float*)d_in[4];
    const float* b_oct = (const float*)d_in[5];
    float* out = (float*)d_out;

    int N = in_sizes[1];          // phi has N elements (N,1,1)

    char* ws = (char*)d_ws;
    float* f0     = (float*)ws;                    // N*250*4
    float* magbar = (float*)(ws + 64 * 1024);      // N*250*4

    k_frames<<<dim3(4 * N), 256, 0, stream>>>(x, w_mag, b_mag, w_oct, b_oct, f0, magbar);
    k_wave<<<dim3(LFRM / RPB, N), 256, 0, stream>>>(f0, magbar, phi, out);
}

// Round 7
// 20.847 us; speedup vs baseline: 3.7949x; 1.1569x over previous
//
#include <hip/hip_runtime.h>
#include <hip/hip_bf16.h>
#include <math.h>

#define SRATE 48000.0
#define SEGSZ 960
#define NHARM 8
#define LFRM 250
#define LWAVE (LFRM * SEGSZ)   // 240000
#define CCH 256
#define RPB 5                  // regions per k_wave block (50*5 = 250)

// ---------------------------------------------------------------------------
// Kernel 1 (R3-verbatim): per-frame 1x1 convs -> f0[n][i], magbar[n][i].
// block = 256 threads = 4 waves; wave wv reduces channels [wv*64, wv*64+64),
// lane = frame index within the 64-frame strip. Weights read with
// wave-uniform addresses -> scalar loads. grid = (N, 4).
// ---------------------------------------------------------------------------
__global__ __launch_bounds__(256) void k_frames(
        const float* __restrict__ x,
        const float* __restrict__ w_mag, const float* __restrict__ b_mag,
        const float* __restrict__ w_oct, const float* __restrict__ b_oct,
        float* __restrict__ f0, float* __restrict__ magbar) {
    __shared__ float sred[NHARM + 1][4][64];
    int tid  = threadIdx.x;
    int lane = tid & 63;
    int wv   = tid >> 6;

    int n = blockIdx.x;
    int i = blockIdx.y * 64 + lane;
    bool act = (i < LFRM);
    int ii = act ? i : (LFRM - 1);
    const float* xp = x + (size_t)n * CCH * LFRM + ii;

    float oct = 0.f;
    float mh[NHARM];
#pragma unroll
    for (int h = 0; h < NHARM; ++h) mh[h] = 0.f;

    int c0 = wv * 64;
#pragma unroll 8
    for (int cc = 0; cc < 64; ++cc) {
        int c = c0 + cc;                     // wave-uniform
        float xv = xp[(size_t)c * LFRM];
        oct = fmaf(w_oct[c], xv, oct);       // uniform addr -> s_load
#pragma unroll
        for (int h = 0; h < NHARM; ++h)
            mh[h] = fmaf(w_mag[h * CCH + c], xv, mh[h]);
    }
    sred[0][wv][lane] = oct;
#pragma unroll
    for (int h = 0; h < NHARM; ++h) sred[1 + h][wv][lane] = mh[h];
    __syncthreads();

    if (tid < 64 && act) {
        float o = sred[0][0][lane] + sred[0][1][lane]
                + sred[0][2][lane] + sred[0][3][lane] + b_oct[0];
        float f0v = 220.0f * exp2f(o);
        float ms = 0.f;
#pragma unroll
        for (int h = 0; h < NHARM; ++h) {
            float mv = sred[1 + h][0][lane] + sred[1 + h][1][lane]
                     + sred[1 + h][2][lane] + sred[1 + h][3][lane];
            ms += expf(fminf(mv + b_mag[h], 6.0f));
        }
        f0[n * LFRM + i]     = f0v;
        magbar[n * LFRM + i] = ms * (1.0f / NHARM);
    }
}

// ---------------------------------------------------------------------------
// Kernel 2 (R3 structure + f32-frac scan): grid = (50, N), block = 256.
// Stage f0/magbar rows to LDS (coalesced, tid<250); wave 0 does the f64
// prefix scan from LDS and emits f32 phase fractions
//   sfr[k] = frac(phi + P[k]),  sfr[250] = frac(phi)   (head base)
// so the synthesis loop is pure f32 (no per-thread f64). 240 active threads,
// regions k = g*5..g*5+4 (k==249 -> head+tail), 4 samples each, float4 store.
// Rel. phase <= ~14 rev in f32 -> ~1e-6 rev error, far under threshold.
// ---------------------------------------------------------------------------
__global__ __launch_bounds__(256) void k_wave(
        const float* __restrict__ f0, const float* __restrict__ magbar,
        const float* __restrict__ phi, float* __restrict__ out) {
    __shared__ float sf0[LFRM];
    __shared__ float smb[LFRM];
    __shared__ float sfr[LFRM + 1];

    int tid = threadIdx.x;
    int n = blockIdx.y;
    int g = blockIdx.x;

    if (tid < LFRM) {
        sf0[tid] = f0[n * LFRM + tid];
        smb[tid] = magbar[n * LFRM + tid];
    }
    __syncthreads();

    if (tid < 64) {                          // wave-0 f64 scan -> f32 fracs
        int lane = tid;
        double ph = (double)phi[n];
        double S[4];
        double local = 0.0;
#pragma unroll
        for (int m = 0; m < 4; ++m) {
            int k = 4 * lane + m;
            double s = 0.0;
            if (k < LFRM - 1)
                s = 480.0 * ((double)sf0[k] + (double)sf0[k + 1]) * (1.0 / SRATE);
            S[m] = s;
            local += s;
        }
        double incl = local;
        for (int off = 1; off < 64; off <<= 1) {
            double up = __shfl_up(incl, off, 64);
            if (lane >= off) incl += up;
        }
        double run = (incl - local) + 480.0 * (double)sf0[0] * (1.0 / SRATE) + ph;
#pragma unroll
        for (int m = 0; m < 4; ++m) {
            int k = 4 * lane + m;
            if (k < LFRM) sfr[k] = (float)(run - floor(run));
            run += S[m];
        }
        if (lane == 0) sfr[LFRM] = (float)(ph - floor(ph));
    }
    __syncthreads();

    if (tid >= 240) return;
    int j0 = tid * 4;

#pragma unroll
    for (int r = 0; r < RPB; ++r) {
        int k = g * RPB + r;
        float rr[4];
        size_t l0;
        if (k < LFRM - 1) {                  // full region k
            float fk = sf0[k];
            float df = sf0[k + 1] - fk;
            float m0 = smb[k];
            float dm = smb[k + 1] - m0;
            float bf = sfr[k];
            float c1 = fk * (float)(1.0 / SRATE);
            float c2 = df * (float)(1.0 / (2.0 * SEGSZ * SRATE));
            l0 = (size_t)(SEGSZ / 2) + (size_t)k * SEGSZ + j0;
#pragma unroll
            for (int q = 0; q < 4; ++q) {
                float mf = (float)(j0 + q + 1);
                float t  = fmaf(mf, c1, fmaf(mf * mf, c2, bf));
                float fr = t - floorf(t);
                float s  = __builtin_amdgcn_sinf(fr);     // sin(2*pi*fr)
                float w  = ((float)(j0 + q) + 0.5f) * (1.0f / SEGSZ);
                rr[q] = s * fmaf(w, dm, m0);
            }
        } else {                             // k == 249: head + tail
            bool tail = (tid >= 120);
            float fk = tail ? sf0[LFRM - 1] : sf0[0];
            float mg = tail ? smb[LFRM - 1] : smb[0];
            float bf = tail ? sfr[LFRM - 1] : sfr[LFRM];
            float c1 = fk * (float)(1.0 / SRATE);
            int jl = (tail ? (tid - 120) : tid) * 4;
            l0 = (tail ? (size_t)(LWAVE - SEGSZ / 2) : 0) + jl;
#pragma unroll
            for (int q = 0; q < 4; ++q) {
                float mf = (float)(jl + q + 1);
                float t  = fmaf(mf, c1, bf);
                float fr = t - floorf(t);
                rr[q] = __builtin_amdgcn_sinf(fr) * mg;
            }
        }
        *reinterpret_cast<float4*>(out + (size_t)n * LWAVE + l0) =
            make_float4(rr[0], rr[1], rr[2], rr[3]);
    }
}

// ---------------------------------------------------------------------------
extern "C" void kernel_launch(void* const* d_in, const int* in_sizes, int n_in,
                              void* d_out, int out_size, void* d_ws, size_t ws_size,
                              hipStream_t stream) {
    const float* x     = (const float*)d_in[0];
    const float* phi   = (const float*)d_in[1];
    const float* w_mag = (const float*)d_in[2];
    const float* b_mag = (const float*)d_in[3];
    const float* w_oct = (const float*)d_in[4];
    const float* b_oct = (const float*)d_in[5];
    float* out = (float*)d_out;

    int N = in_sizes[1];          // phi has N elements (N,1,1)

    char* ws = (char*)d_ws;
    float* f0     = (float*)ws;                    // N*250*4
    float* magbar = (float*)(ws + 64 * 1024);      // N*250*4

    k_frames<<<dim3(N, 4), 256, 0, stream>>>(x, w_mag, b_mag, w_oct, b_oct, f0, magbar);
    k_wave<<<dim3(LFRM / RPB, N), 256, 0, stream>>>(f0, magbar, phi, out);
}